// Round 2
// baseline (715.735 us; speedup 1.0000x reference)
//
#include <hip/hip_runtime.h>
#include <hip/hip_bf16.h>
#include <math.h>

// Problem constants
#define B_  2
#define T_  1024
#define D_  1024
#define H_  16
#define DK_ 64
#define DV_ 128
#define FH_ 2816
#define M_  (B_ * T_)   // 2048 tokens
#define C_  64          // chunk length
#define NCH (T_ / C_)   // 16 chunks

typedef __attribute__((ext_vector_type(8))) short bf16x8;
typedef __attribute__((ext_vector_type(4))) float f32x4;

// ---------------------------------------------------------------------------
// rmsnorm with fp32 and/or bf16 outputs (either may be null)
__global__ __launch_bounds__(256) void rmsnorm_k(
    const float* __restrict__ x, const float* __restrict__ w,
    float* __restrict__ outf, __hip_bfloat16* __restrict__ outb,
    int D, float eps) {
  const int row = blockIdx.x;
  const float* xr = x + (size_t)row * D;
  float ss = 0.f;
  for (int i = threadIdx.x; i < D; i += blockDim.x) { float v = xr[i]; ss += v * v; }
  for (int off = 32; off > 0; off >>= 1) ss += __shfl_xor(ss, off, 64);
  __shared__ float wsum[4];
  __shared__ float s_scale;
  const int lane = threadIdx.x & 63, wid = threadIdx.x >> 6;
  if (lane == 0) wsum[wid] = ss;
  __syncthreads();
  if (threadIdx.x == 0) {
    float tot = 0.f;
    const int nw = blockDim.x >> 6;
    for (int i = 0; i < nw; ++i) tot += wsum[i];
    s_scale = rsqrtf(tot / (float)D + eps);
  }
  __syncthreads();
  const float sc = s_scale;
  for (int i = threadIdx.x; i < D; i += blockDim.x) {
    const float v = xr[i] * sc * w[i];
    if (outf) outf[(size_t)row * D + i] = v;
    if (outb) outb[(size_t)row * D + i] = __float2bfloat16(v);
  }
}

// ---------------------------------------------------------------------------
// Tiled transpose + fp32->bf16 convert: W[K,N] -> Wt[N,K]
__global__ __launch_bounds__(256) void transpose_bf16_k(
    const float* __restrict__ W, __hip_bfloat16* __restrict__ Wt, int K, int N) {
  __shared__ float t[32][33];
  const int k0 = blockIdx.y * 32, n0 = blockIdx.x * 32;
  const int c = threadIdx.x & 31, r = threadIdx.x >> 5;  // r in 0..7
#pragma unroll
  for (int i = 0; i < 4; ++i)
    t[r + 8 * i][c] = W[(size_t)(k0 + r + 8 * i) * N + n0 + c];
  __syncthreads();
#pragma unroll
  for (int i = 0; i < 4; ++i)
    Wt[(size_t)(n0 + r + 8 * i) * K + k0 + c] = __float2bfloat16(t[c][r + 8 * i]);
}

// ---------------------------------------------------------------------------
__device__ __forceinline__ void gload_lds16(const void* g, void* l) {
  __builtin_amdgcn_global_load_lds(
      (const __attribute__((address_space(1))) void*)g,
      (__attribute__((address_space(3))) void*)l, 16, 0, 0);
}

// bf16 MFMA GEMM: C[M,N] = A[M,K] @ Bt[N,K]^T.  Tile 128 x BN (BN=128 or 64).
// BN=64 doubles the grid for N=1024 shapes (128 WGs only covered half the CUs).
// mode 0: C = acc (fp32); mode 1: C = acc + res (fp32);
// mode 2: Cbf16 = silu(res) * acc   (fused SwiGLU epilogue)
template<int BN>
__global__ __launch_bounds__(256) void mfma_gemm_k(
    const __hip_bfloat16* __restrict__ A, const __hip_bfloat16* __restrict__ Bt,
    const float* __restrict__ res, void* __restrict__ Cout,
    int M, int N, int K, int mode) {
  __shared__ __hip_bfloat16 As[128 * 32];
  __shared__ __hip_bfloat16 Bs[BN * 32];
  constexpr int NF = BN / 32;        // b-frags per wave (4 or 2)
  const int tid = threadIdx.x;
  const int lane = tid & 63;
  const int wv = tid >> 6;
  const int wm = (wv >> 1) * 64, wn = (wv & 1) * (BN / 2);
  const int bm = blockIdx.y * 128, bn = blockIdx.x * BN;
  const int l15 = lane & 15, lq8 = (lane >> 4) * 8;
  const int ar = tid >> 2;
  const int ac = (tid & 3) * 8;
  const size_t Abase = (size_t)(bm + ar) * K + ac;
  const size_t Bbase = (size_t)(bn + ar) * K + ac;
  f32x4 acc[4][NF];
#pragma unroll
  for (int i = 0; i < 4; ++i)
#pragma unroll
    for (int j = 0; j < NF; ++j) acc[i][j] = (f32x4){0.f, 0.f, 0.f, 0.f};
  for (int k0 = 0; k0 < K; k0 += 32) {
    gload_lds16(A + Abase + k0, (char*)As + tid * 16);
    gload_lds16(A + Abase + (size_t)64 * K + k0, (char*)As + tid * 16 + 4096);
    gload_lds16(Bt + Bbase + k0, (char*)Bs + tid * 16);
    if (BN == 128)
      gload_lds16(Bt + Bbase + (size_t)64 * K + k0, (char*)Bs + tid * 16 + 4096);
    __syncthreads();
    bf16x8 af[4], bfr[NF];
#pragma unroll
    for (int i = 0; i < 4; ++i)
      af[i] = *(const bf16x8*)(As + (wm + i * 16 + l15) * 32 + lq8);
#pragma unroll
    for (int j = 0; j < NF; ++j)
      bfr[j] = *(const bf16x8*)(Bs + (wn + j * 16 + l15) * 32 + lq8);
#pragma unroll
    for (int i = 0; i < 4; ++i)
#pragma unroll
      for (int j = 0; j < NF; ++j)
        acc[i][j] = __builtin_amdgcn_mfma_f32_16x16x32_bf16(af[i], bfr[j], acc[i][j], 0, 0, 0);
    __syncthreads();
  }
  const int r0 = (lane >> 4) * 4;
#pragma unroll
  for (int i = 0; i < 4; ++i) {
#pragma unroll
    for (int j = 0; j < NF; ++j) {
      const int row = bm + wm + i * 16 + r0;
      const int col = bn + wn + j * 16 + l15;
#pragma unroll
      for (int r = 0; r < 4; ++r) {
        const size_t idx = (size_t)(row + r) * N + col;
        const float a = acc[i][j][r];
        if (mode == 0) ((float*)Cout)[idx] = a;
        else if (mode == 1) ((float*)Cout)[idx] = a + res[idx];
        else {
          const float s = res[idx];
          ((__hip_bfloat16*)Cout)[idx] =
              __float2bfloat16(s * (1.f / (1.f + __expf(-s))) * a);
        }
      }
    }
  }
}

// ---------------------------------------------------------------------------
// pa/pb = h @ [Wa|Wb] — all 256 threads active (8-way K-split + reduce).
__global__ __launch_bounds__(256) void skinny_k(
    const float* __restrict__ h, const float* __restrict__ Wa,
    const float* __restrict__ Wb, float* __restrict__ pa,
    float* __restrict__ pb, int K) {
  __shared__ float hl[D_];
  __shared__ float red[8][32];
  const int row = blockIdx.x;
  const int tid = threadIdx.x;
  {
    const float4* src = (const float4*)(h + (size_t)row * K);
    ((float4*)hl)[tid] = src[tid];
  }
  __syncthreads();
  const int col = tid & 31, sub = tid >> 5;
  const float* W = (col < 16) ? Wa : Wb;
  const int cc = col & 15;
  float s = 0.f;
  const int kk0 = sub * 128;
  for (int k = kk0; k < kk0 + 128; ++k) s += hl[k] * W[k * H_ + cc];
  red[sub][col] = s;
  __syncthreads();
  if (tid < 32) {
    float t = 0.f;
#pragma unroll
    for (int i = 0; i < 8; ++i) t += red[i][tid];
    if (tid < 16) pa[(size_t)row * H_ + tid] = t;
    else          pb[(size_t)row * H_ + tid - 16] = t;
  }
}

// ---------------------------------------------------------------------------
__global__ __launch_bounds__(256) void conv_silu_k(
    const float* __restrict__ src, const float* __restrict__ w,
    float* __restrict__ dst, int C) {
  const int bt = blockIdx.x;
  const int b = bt / T_, t = bt % T_;
  const float* s = src + (size_t)b * T_ * C;
  for (int c = threadIdx.x; c < C; c += blockDim.x) {
    const float w0 = w[c * 4 + 0], w1 = w[c * 4 + 1],
                w2 = w[c * 4 + 2], w3 = w[c * 4 + 3];
    float acc = s[(size_t)t * C + c] * w3;
    if (t >= 1) acc += s[(size_t)(t - 1) * C + c] * w2;
    if (t >= 2) acc += s[(size_t)(t - 2) * C + c] * w1;
    if (t >= 3) acc += s[(size_t)(t - 3) * C + c] * w0;
    dst[(size_t)bt * C + c] = acc * (1.f / (1.f + __expf(-acc)));
  }
}

// ---------------------------------------------------------------------------
__global__ void beta_g_k(const float* __restrict__ pa, const float* __restrict__ pb,
                         const float* __restrict__ dtb, const float* __restrict__ Alog,
                         float* __restrict__ g, float* __restrict__ beta, int n) {
  const int i = blockIdx.x * blockDim.x + threadIdx.x;
  if (i >= n) return;
  const int h = i & (H_ - 1);
  const float xx = pa[i] + dtb[h];
  const float sp = (xx > 20.f) ? xx : log1pf(expf(xx));
  g[i] = -expf(Alog[h]) * sp;
  beta[i] = 1.f / (1.f + expf(-pb[i]));
}

// ---------------------------------------------------------------------------
__global__ __launch_bounds__(64) void l2norm_k(float* __restrict__ q, float scale) {
  const size_t row = blockIdx.x;
  const int lane = threadIdx.x;
  const float v = q[row * 64 + lane];
  float ss = v * v;
  for (int off = 32; off > 0; off >>= 1) ss += __shfl_xor(ss, off, 64);
  q[row * 64 + lane] = v * rsqrtf(ss + 1e-6f) * scale;
}

// ---------------------------------------------------------------------------
// Chunked gated delta rule, phase A v3 (parallel over 512 (bh,chunk) tasks).
// Builds G (β-folded strict-lower decay Gram), QKd (->qkd), KdT (->kdt), γ.
// Then solves (I+G)X = RHS directly via BLOCKED forward substitution:
// 16x16 diagonal-block inverses Td (per-thread register triangles), then a
// 4-stage dense sweep over 96-column halves in LDS. Replaces round-4/6's
// Neumann doubling (10 x 64^3 matmuls -> ~1M MACs total, 4x less VALU).
// Outputs: u = X (in place over v), W = X (in place over k).
__global__ __launch_bounds__(256) void chunk_prep_k(
    const float* __restrict__ q, float* __restrict__ k, float* __restrict__ v,
    const float* __restrict__ g, const float* __restrict__ beta,
    float* __restrict__ qkd, float* __restrict__ kdt, float* __restrict__ gam) {
  const int task = blockIdx.x;
  const int bh = task >> 4, n = task & (NCH - 1);
  const int b = bh >> 4, h = bh & 15;
  const int t0 = n * C_;
  const int tid = threadIdx.x;
  __shared__ float lk[C_][68];     // staged k rows
  __shared__ float Gs[C_][68];     // strict-lower β-folded Gram (zeros above)
  __shared__ float Xs[C_][100];    // 96-column RHS/solution panel
  __shared__ float Td[4][16][17];  // 16x16 diagonal-block inverses
  __shared__ float lb[C_], lgam[C_], lbeta[C_], lbg[C_];
  // stage k chunk
  {
    const int r = tid >> 2, cq = (tid & 3) * 16;
    const float* src = k + (((size_t)b * T_ + t0 + r) * H_ + h) * DK_ + cq;
#pragma unroll
    for (int i = 0; i < 4; ++i)
      *(float4*)&lk[r][cq + 4 * i] = ((const float4*)src)[i];
  }
  // g cumsum (wave 0), γ, β, βγ
  if (tid < 64) {
    const size_t gi = ((size_t)b * T_ + t0 + tid) * H_ + h;
    float xx = g[gi];
    const float bb = beta[gi];
    lbeta[tid] = bb;
#pragma unroll
    for (int off = 1; off < 64; off <<= 1) {
      float y = __shfl_up(xx, off, 64);
      if (tid >= off) xx += y;
    }
    lb[tid] = xx;
    const float gm = __expf(xx);
    lgam[tid] = gm;
    lbg[tid] = bb * gm;
  }
  __syncthreads();
  const int r4g = (tid >> 4) * 4;
  const int sl = tid & 15;
  // Gram: G = β-folded strict-lower K K^T decay; QKd = (Q K^T) decay
  {
    const float* qg = q + (((size_t)b * T_ + t0) * H_ + h) * DK_;
    float accA[4][4] = {};
    float accQ[4][4] = {};
    for (int d = 0; d < 64; d += 4) {
      float4 kt[4], ks[4], qt[4];
#pragma unroll
      for (int i = 0; i < 4; ++i) kt[i] = *(const float4*)&lk[r4g + i][d];
#pragma unroll
      for (int j = 0; j < 4; ++j) ks[j] = *(const float4*)&lk[sl + 16 * j][d];
#pragma unroll
      for (int i = 0; i < 4; ++i) qt[i] = *(const float4*)(qg + (size_t)(r4g + i) * (H_ * DK_) + d);
#pragma unroll
      for (int i = 0; i < 4; ++i)
#pragma unroll
        for (int j = 0; j < 4; ++j) {
          accA[i][j] += kt[i].x * ks[j].x + kt[i].y * ks[j].y + kt[i].z * ks[j].z + kt[i].w * ks[j].w;
          accQ[i][j] += qt[i].x * ks[j].x + qt[i].y * ks[j].y + qt[i].z * ks[j].z + qt[i].w * ks[j].w;
        }
    }
    float* qo = qkd + (size_t)task * 4096;
#pragma unroll
    for (int i = 0; i < 4; ++i)
#pragma unroll
      for (int j = 0; j < 4; ++j) {
        const int t = r4g + i, s = sl + 16 * j;
        const float dec = (s <= t) ? __expf(lb[t] - lb[s]) : 0.f;
        Gs[t][s] = (t > s) ? lbeta[t] * accA[i][j] * dec : 0.f;
        qo[t * 64 + s] = accQ[i][j] * dec;
      }
  }
  // KdT and γ out
  {
    const int dk = tid >> 2, s0 = (tid & 3) * 16;
    const float bC = lb[63];
    float* dst = kdt + (size_t)task * 4096 + dk * 64 + s0;
#pragma unroll
    for (int j = 0; j < 16; ++j)
      dst[j] = lk[s0 + j][dk] * __expf(bC - lb[s0 + j]);
  }
  if (tid < 64) gam[(size_t)task * 64 + tid] = lgam[tid];
  __syncthreads();
  // Td (threads 0..63: 4 blocks x 16 columns, registers only) + RHS0 load
  if (tid < 64) {
    const int blk = tid >> 4, cI = tid & 15;
    float Xc[16];
#pragma unroll
    for (int t = 0; t < 16; ++t) Xc[t] = (t == cI) ? 1.f : 0.f;
#pragma unroll
    for (int t = 1; t < 16; ++t) {
      float acc = 0.f;
#pragma unroll
      for (int s = 0; s < t; ++s)
        acc += Gs[blk * 16 + t][blk * 16 + s] * Xc[s];
      Xc[t] -= acc;
    }
#pragma unroll
    for (int t = 0; t < 16; ++t) Td[blk][t][cI] = Xc[t];
  } else {
    // RHS half 0: βV columns 0..95 (192 threads, 32 cells each)
    for (int idx = tid - 64; idx < 64 * 96; idx += 192) {
      const int t = idx / 96, c = idx % 96;
      Xs[t][c] = lbeta[t] * v[(((size_t)b * T_ + t0 + t) * H_ + h) * DV_ + c];
    }
  }
  __syncthreads();
  const int rt = tid & 15;          // row within block
  const int cg = tid >> 4;          // column group: cols cg*6 .. cg*6+5
#pragma unroll 1
  for (int half = 0; half < 2; ++half) {
    // 4-stage blocked sweep
#pragma unroll
    for (int bi = 0; bi < 4; ++bi) {
      if (bi > 0) {
        float acc[6] = {0.f, 0.f, 0.f, 0.f, 0.f, 0.f};
        for (int kk = 0; kk < 16 * bi; ++kk) {
          const float gvv = Gs[16 * bi + rt][kk];
#pragma unroll
          for (int c = 0; c < 6; ++c) acc[c] += gvv * Xs[kk][cg * 6 + c];
        }
#pragma unroll
        for (int c = 0; c < 6; ++c) Xs[16 * bi + rt][cg * 6 + c] -= acc[c];
      }
      __syncthreads();
      float y[6] = {0.f, 0.f, 0.f, 0.f, 0.f, 0.f};
#pragma unroll
      for (int s = 0; s < 16; ++s) {
        const float tv = Td[bi][rt][s];
#pragma unroll
        for (int c = 0; c < 6; ++c) y[c] += tv * Xs[16 * bi + s][cg * 6 + c];
      }
      __syncthreads();
#pragma unroll
      for (int c = 0; c < 6; ++c) Xs[16 * bi + rt][cg * 6 + c] = y[c];
      __syncthreads();
    }
    // writeback + next RHS
    if (half == 0) {
      for (int idx = tid; idx < 64 * 96; idx += 256) {
        const int t = idx / 96, c = idx % 96;
        v[(((size_t)b * T_ + t0 + t) * H_ + h) * DV_ + c] = Xs[t][c];
      }
      __syncthreads();
      // RHS half 1: cols 0..31 = βV cols 96..127; cols 32..95 = βγ·K cols 0..63
      for (int idx = tid; idx < 64 * 96; idx += 256) {
        const int t = idx / 96, c = idx % 96;
        if (c < 32)
          Xs[t][c] = lbeta[t] * v[(((size_t)b * T_ + t0 + t) * H_ + h) * DV_ + 96 + c];
        else
          Xs[t][c] = lbg[t] * lk[t][c - 32];
      }
      __syncthreads();
    } else {
      for (int idx = tid; idx < 64 * 96; idx += 256) {
        const int t = idx / 96, c = idx % 96;
        if (c < 32)
          v[(((size_t)b * T_ + t0 + t) * H_ + h) * DV_ + 96 + c] = Xs[t][c];
        else
          k[(((size_t)b * T_ + t0 + t) * H_ + h) * DK_ + c - 32] = Xs[t][c];
      }
    }
  }
}

// ---------------------------------------------------------------------------
// Serial recurrence — round 7: register-prefetch software pipeline.
// rocprof (round 6): 84.7us, VALUBusy 9.3%, Occ 2.7%, HBM 17% => latency-bound.
// Per-chunk compute floor ~2.2us vs 5.3us measured: ~3us/chunk is exposed
// global-load latency at the top of each serial iteration (W/kdt/u loads,
// 1 wave/CU => no TLP to hide it). Fix: preload chunk 0 into registers;
// each iteration commits regs->LDS, then issues chunk n+1 loads into the
// same regs (static float4 arrays, fully unrolled => stays in VGPRs), then
// runs the two 64x64x16 matmuls (~5000cy) which cover the ~900cy latency.
__global__ __launch_bounds__(64) void chunk_rec_k(
    const float* __restrict__ W, float* __restrict__ u,
    const float* __restrict__ kdt, const float* __restrict__ gam,
    float* __restrict__ Sst) {
  const int bh = blockIdx.x >> 3, cg = blockIdx.x & 7;
  const int b = bh >> 4, h = bh & 15;
  const int c0 = cg * 16;
  const int lane = threadIdx.x;
  const int r4 = (lane & 15) * 4;
  const int cl = (lane >> 4) * 4;
  __shared__ float Wt[64][68];
  __shared__ float Kt[64][68];
  __shared__ float Ss[64][20];
  __shared__ float Ub[64][20];
  float Sr[4][4];
#pragma unroll
  for (int i = 0; i < 4; ++i)
#pragma unroll
    for (int j = 0; j < 4; ++j) Sr[i][j] = 0.f;
  for (int i = lane; i < 64 * 20; i += 64) (&Ss[0][0])[i] = 0.f;

  // prefetch registers (144 VGPRs) — chunk 0
  float4 rW[16], rK[16], rU[4];
  float gC_nxt;
  {
    const float* srcW = W + (((size_t)b * T_ + lane) * H_ + h) * DK_;
    const float* srcK = kdt + (size_t)(bh * NCH) * 4096 + lane * 64;
#pragma unroll
    for (int i = 0; i < 16; ++i) rW[i] = ((const float4*)srcW)[i];
#pragma unroll
    for (int i = 0; i < 16; ++i) rK[i] = ((const float4*)srcK)[i];
#pragma unroll
    for (int i = 0; i < 4; ++i)
      rU[i] = *(const float4*)(u + (((size_t)b * T_ + r4 + i) * H_ + h) * DV_ + c0 + cl);
    gC_nxt = gam[(size_t)(bh * NCH) * 64 + 63];
  }

#pragma unroll 1
  for (int n = 0; n < NCH; ++n) {
    const int task = bh * NCH + n;
    const int t0 = n * C_;
    const float gC = gC_nxt;
    // commit prefetched regs to LDS (transposed staging)
#pragma unroll
    for (int d4 = 0; d4 < 16; ++d4) {
      Wt[4 * d4 + 0][lane] = rW[d4].x; Wt[4 * d4 + 1][lane] = rW[d4].y;
      Wt[4 * d4 + 2][lane] = rW[d4].z; Wt[4 * d4 + 3][lane] = rW[d4].w;
    }
#pragma unroll
    for (int s4 = 0; s4 < 16; ++s4) {
      Kt[4 * s4 + 0][lane] = rK[s4].x; Kt[4 * s4 + 1][lane] = rK[s4].y;
      Kt[4 * s4 + 2][lane] = rK[s4].z; Kt[4 * s4 + 3][lane] = rK[s4].w;
    }
    float acc[4][4];
#pragma unroll
    for (int i = 0; i < 4; ++i) {
      acc[i][0] = rU[i].x; acc[i][1] = rU[i].y;
      acc[i][2] = rU[i].z; acc[i][3] = rU[i].w;
    }
    // state snapshot out (pre-chunk state, consumed by chunk_o_k)
#pragma unroll
    for (int i = 0; i < 4; ++i)
      *(float4*)(Sst + (size_t)task * 8192 + (r4 + i) * 128 + c0 + cl) =
          make_float4(Sr[i][0], Sr[i][1], Sr[i][2], Sr[i][3]);
    // issue chunk n+1 loads — hidden under the two matmuls below
    if (n + 1 < NCH) {
      const int t1 = t0 + C_;
      const float* srcW = W + (((size_t)b * T_ + t1 + lane) * H_ + h) * DK_;
      const float* srcK = kdt + (size_t)(task + 1) * 4096 + lane * 64;
#pragma unroll
      for (int i = 0; i < 16; ++i) rW[i] = ((const float4*)srcW)[i];
#pragma unroll
      for (int i = 0; i < 16; ++i) rK[i] = ((const float4*)srcK)[i];
#pragma unroll
      for (int i = 0; i < 4; ++i)
        rU[i] = *(const float4*)(u + (((size_t)b * T_ + t1 + r4 + i) * H_ + h) * DV_ + c0 + cl);
      gC_nxt = gam[(size_t)(task + 1) * 64 + 63];
    }
    // matmul 1: U = u - W @ S
    for (int kb = 0; kb < 64; kb += 4) {
#pragma unroll
      for (int j = 0; j < 4; ++j) {
        const float4 a = *(const float4*)&Wt[kb + j][r4];
        const float4 bb = *(const float4*)&Ss[kb + j][cl];
        const float av[4] = {a.x, a.y, a.z, a.w};
        const float bv[4] = {bb.x, bb.y, bb.z, bb.w};
#pragma unroll
        for (int i = 0; i < 4; ++i)
#pragma unroll
          for (int c = 0; c < 4; ++c) acc[i][c] -= av[i] * bv[c];
      }
    }
#pragma unroll
    for (int i = 0; i < 4; ++i) {
      *(float4*)&Ub[r4 + i][cl] = make_float4(acc[i][0], acc[i][1], acc[i][2], acc[i][3]);
      *(float4*)(u + (((size_t)b * T_ + t0 + r4 + i) * H_ + h) * DV_ + c0 + cl) =
          make_float4(acc[i][0], acc[i][1], acc[i][2], acc[i][3]);
    }
    // matmul 2: S' = γ S + K̂ᵀ @ U
    float acc2[4][4] = {};
    for (int sb = 0; sb < 64; sb += 4) {
#pragma unroll
      for (int j = 0; j < 4; ++j) {
        const float4 a = *(const float4*)&Kt[sb + j][r4];
        const float4 bb = *(const float4*)&Ub[sb + j][cl];
        const float av[4] = {a.x, a.y, a.z, a.w};
        const float bv[4] = {bb.x, bb.y, bb.z, bb.w};
#pragma unroll
        for (int i = 0; i < 4; ++i)
#pragma unroll
          for (int c = 0; c < 4; ++c) acc2[i][c] += av[i] * bv[c];
      }
    }
#pragma unroll
    for (int i = 0; i < 4; ++i)
#pragma unroll
      for (int c = 0; c < 4; ++c) Sr[i][c] = gC * Sr[i][c] + acc2[i][c];
#pragma unroll
    for (int i = 0; i < 4; ++i)
      *(float4*)&Ss[r4 + i][cl] = make_float4(Sr[i][0], Sr[i][1], Sr[i][2], Sr[i][3]);
  }
}

// ---------------------------------------------------------------------------
// Parallel O with fused gatenorm (unchanged from round 6).
__global__ __launch_bounds__(128) void chunk_o_k(
    const float* __restrict__ q, const float* __restrict__ qkd,
    const float* __restrict__ ub, const float* __restrict__ Sst,
    const float* __restrict__ gam, const float* __restrict__ gate,
    const float* __restrict__ onw, __hip_bfloat16* __restrict__ go) {
  const int task = blockIdx.x;
  const int bh = task >> 4, n = task & 15;
  const int b = bh >> 4, h = bh & 15;
  const int t0 = n * C_;
  const int tid = threadIdx.x;
  const int rowg = tid >> 4, colg = tid & 15;
  const int r8 = rowg * 8, c4 = colg * 4;
  __shared__ float At[64][68];
  __shared__ float Bs[64][132];
  __shared__ float lgam[64];
  if (tid < 64) lgam[tid] = gam[(size_t)task * 64 + tid];
  __syncthreads();
  const int t2 = tid >> 1, dh = (tid & 1) * 32;
  {
    const float* src = q + (((size_t)b * T_ + t0 + t2) * H_ + h) * DK_ + dh;
    const float sc = lgam[t2];
#pragma unroll
    for (int i = 0; i < 8; ++i) {
      const float4 v = ((const float4*)src)[i];
      At[dh + 4 * i + 0][t2] = v.x * sc; At[dh + 4 * i + 1][t2] = v.y * sc;
      At[dh + 4 * i + 2][t2] = v.z * sc; At[dh + 4 * i + 3][t2] = v.w * sc;
    }
  }
  {
    const float* src = Sst + (size_t)task * 8192 + t2 * 128 + (tid & 1) * 64;
    float* dst = &Bs[t2][(tid & 1) * 64];
#pragma unroll
    for (int i = 0; i < 16; ++i) ((float4*)dst)[i] = ((const float4*)src)[i];
  }
  __syncthreads();
  float acc[8][8];
#pragma unroll
  for (int i = 0; i < 8; ++i)
#pragma unroll
    for (int c = 0; c < 8; ++c) acc[i][c] = 0.f;
#pragma unroll 1
  for (int ph = 0; ph < 2; ++ph) {
    for (int kb = 0; kb < 64; kb += 4) {
#pragma unroll
      for (int j = 0; j < 4; ++j) {
        const float4 alo = *(const float4*)&At[kb + j][r8];
        const float4 ahi = *(const float4*)&At[kb + j][r8 + 4];
        const float4 blo = *(const float4*)&Bs[kb + j][c4];
        const float4 bhi = *(const float4*)&Bs[kb + j][c4 + 64];
        const float av[8] = {alo.x, alo.y, alo.z, alo.w, ahi.x, ahi.y, ahi.z, ahi.w};
        const float bv[8] = {blo.x, blo.y, blo.z, blo.w, bhi.x, bhi.y, bhi.z, bhi.w};
#pragma unroll
        for (int i = 0; i < 8; ++i)
#pragma unroll
          for (int c = 0; c < 8; ++c) acc[i][c] += av[i] * bv[c];
      }
    }
    if (ph == 0) {
      __syncthreads();
      {
        const float* src = qkd + (size_t)task * 4096 + t2 * 64 + dh;
#pragma unroll
        for (int i = 0; i < 8; ++i) {
          const float4 v = ((const float4*)src)[i];
          At[dh + 4 * i + 0][t2] = v.x; At[dh + 4 * i + 1][t2] = v.y;
          At[dh + 4 * i + 2][t2] = v.z; At[dh + 4 * i + 3][t2] = v.w;
        }
      }
      {
        const float* src = ub + (((size_t)b * T_ + t0 + t2) * H_ + h) * DV_ + (tid & 1) * 64;
        float* dst = &Bs[t2][(tid & 1) * 64];
#pragma unroll
        for (int i = 0; i < 16; ++i) ((float4*)dst)[i] = ((const float4*)src)[i];
      }
      __syncthreads();
    }
  }
#pragma unroll
  for (int i = 0; i < 8; ++i) {
    float pr = 0.f;
#pragma unroll
    for (int c = 0; c < 8; ++c) pr += acc[i][c] * acc[i][c];
    pr += __shfl_xor(pr, 1, 64);
    pr += __shfl_xor(pr, 2, 64);
    pr += __shfl_xor(pr, 4, 64);
    pr += __shfl_xor(pr, 8, 64);
    const float rms = rsqrtf(pr / (float)DV_ + 1e-5f);
    const size_t rb = (((size_t)b * T_ + t0 + r8 + i) * H_ + h) * DV_;
    const float4 glo = *(const float4*)(gate + rb + c4);
    const float4 ghi = *(const float4*)(gate + rb + c4 + 64);
    const float gv[8] = {glo.x, glo.y, glo.z, glo.w, ghi.x, ghi.y, ghi.z, ghi.w};
    unsigned short outv[8];
#pragma unroll
    for (int c = 0; c < 8; ++c) {
      const int col = (c < 4) ? c4 + c : c4 + 60 + c;
      const float gg = gv[c];
      const float val = acc[i][c] * rms * onw[col] * gg * (1.f / (1.f + __expf(-gg)));
      const __hip_bfloat16 bfv = __float2bfloat16(val);
      outv[c] = *(const unsigned short*)&bfv;
    }
    *(ushort4*)((unsigned short*)go + rb + c4) =
        make_ushort4(outv[0], outv[1], outv[2], outv[3]);
    *(ushort4*)((unsigned short*)go + rb + c4 + 64) =
        make_ushort4(outv[4], outv[5], outv[6], outv[7]);
  }
}

// ---------------------------------------------------------------------------
extern "C" void kernel_launch(void* const* d_in, const int* in_sizes, int n_in,
                              void* d_out, int out_size, void* d_ws, size_t ws_size,
                              hipStream_t stream) {
  const float* x    = (const float*)d_in[0];
  const float* n1w  = (const float*)d_in[1];
  const float* n2w  = (const float*)d_in[2];
  const float* Wq   = (const float*)d_in[3];
  const float* Wk   = (const float*)d_in[4];
  const float* Wv   = (const float*)d_in[5];
  const float* cq   = (const float*)d_in[6];
  const float* ck   = (const float*)d_in[7];
  const float* cv   = (const float*)d_in[8];
  const float* Wa   = (const float*)d_in[9];
  const float* Wb   = (const float*)d_in[10];
  const float* dtb  = (const float*)d_in[11];
  const float* Alog = (const float*)d_in[12];
  const float* Wg   = (const float*)d_in[13];
  const float* onw  = (const float*)d_in[14];
  const float* Wo   = (const float*)d_in[15];
  const float* W1   = (const float*)d_in[16];
  const float* W3   = (const float*)d_in[17];
  const float* W2   = (const float*)d_in[18];
  float* out = (float*)d_out;
  float* ws  = (float*)d_ws;

  const size_t SZ_MD = (size_t)M_ * D_;          // 2M floats
  const size_t SZ_MV = (size_t)M_ * H_ * DV_;    // 4M floats
  float* h    = ws;                               // [0,2M)
  float* pq   = ws + SZ_MD;                       // [2M,4M)  -> QKd -> y1
  float* pk   = ws + 2 * SZ_MD;                   // [4M,6M)  -> KdT
  float* pv   = ws + 3 * SZ_MD;                   // [6M,10M) -> S_store -> a1
  float* gate = ws + 3 * SZ_MD + SZ_MV;           // [10M,14M)
  float* qb   = ws + 3 * SZ_MD + 2 * SZ_MV;       // [14M,16M)
  float* kb   = ws + 4 * SZ_MD + 2 * SZ_MV;       // [16M,18M) in-place W
  float* vb   = ws + 5 * SZ_MD + 2 * SZ_MV;       // [18M,22M) in-place u -> Û
  float* Sst  = pv;
  float* y1   = pq;
  float* a1   = pv;
  float* smalls = ws + 5 * SZ_MD + 3 * SZ_MV;     // 22M
  float* pa  = smalls;
  float* pb  = pa + (size_t)M_ * H_;
  float* gv  = pb + (size_t)M_ * H_;
  float* bv  = gv + (size_t)M_ * H_;
  float* gam = bv + (size_t)M_ * H_;
  __hip_bfloat16* h_bf  = (__hip_bfloat16*)vb;
  __hip_bfloat16* wb1   = (__hip_bfloat16*)kb;
  __hip_bfloat16* wb2   = (__hip_bfloat16*)vb;
  __hip_bfloat16* go_bf = (__hip_bfloat16*)h;
  __hip_bfloat16* h2_bf = (__hip_bfloat16*)h;
  __hip_bfloat16* a1b   = (__hip_bfloat16*)qb;

  const dim3 blk256(256);
  const dim3 g_tr1024_1024(1024 / 32, 1024 / 32);
  const dim3 g_tr1024_2048(2048 / 32, 1024 / 32);
  const dim3 g_tr2048_1024(1024 / 32, 2048 / 32);
  const dim3 g_tr1024_2816(2816 / 32, 1024 / 32);
  const dim3 g_tr2816_1024(1024 / 32, 2816 / 32);

  rmsnorm_k<<<dim3(M_), blk256, 0, stream>>>(x, n1w, h, h_bf, D_, 1e-6f);
  transpose_bf16_k<<<g_tr1024_1024, blk256, 0, stream>>>(Wq, wb1, D_, 1024);
  mfma_gemm_k<64><<<dim3(1024 / 64, M_ / 128), blk256, 0, stream>>>(h_bf, wb1, nullptr, pq, M_, 1024, D_, 0);
  transpose_bf16_k<<<g_tr1024_1024, blk256, 0, stream>>>(Wk, wb1, D_, 1024);
  mfma_gemm_k<64><<<dim3(1024 / 64, M_ / 128), blk256, 0, stream>>>(h_bf, wb1, nullptr, pk, M_, 1024, D_, 0);
  transpose_bf16_k<<<g_tr1024_2048, blk256, 0, stream>>>(Wv, wb1, D_, 2048);
  mfma_gemm_k<128><<<dim3(2048 / 128, M_ / 128), blk256, 0, stream>>>(h_bf, wb1, nullptr, pv, M_, 2048, D_, 0);
  transpose_bf16_k<<<g_tr1024_2048, blk256, 0, stream>>>(Wg, wb1, D_, 2048);
  mfma_gemm_k<128><<<dim3(2048 / 128, M_ / 128), blk256, 0, stream>>>(h_bf, wb1, nullptr, gate, M_, 2048, D_, 0);
  skinny_k<<<dim3(M_), blk256, 0, stream>>>(h, Wa, Wb, pa, pb, D_);
  conv_silu_k<<<dim3(M_), blk256, 0, stream>>>(pq, cq, qb, H_ * DK_);
  conv_silu_k<<<dim3(M_), blk256, 0, stream>>>(pk, ck, kb, H_ * DK_);
  conv_silu_k<<<dim3(M_), blk256, 0, stream>>>(pv, cv, vb, H_ * DV_);
  beta_g_k<<<dim3((M_ * H_ + 255) / 256), blk256, 0, stream>>>(pa, pb, dtb, Alog, gv, bv, M_ * H_);
  l2norm_k<<<dim3(M_ * H_), dim3(64), 0, stream>>>(qb, 0.125f);
  l2norm_k<<<dim3(M_ * H_), dim3(64), 0, stream>>>(kb, 1.0f);
  chunk_prep_k<<<dim3(32 * NCH), blk256, 0, stream>>>(qb, kb, vb, gv, bv, pq, pk, gam);
  chunk_rec_k<<<dim3(32 * 8), dim3(64), 0, stream>>>(kb, vb, pk, gam, Sst);
  chunk_o_k<<<dim3(32 * NCH), dim3(128), 0, stream>>>(qb, pq, vb, Sst, gam, gate, onw, go_bf);
  transpose_bf16_k<<<g_tr2048_1024, blk256, 0, stream>>>(Wo, wb2, H_ * DV_, 1024);
  mfma_gemm_k<64><<<dim3(1024 / 64, M_ / 128), blk256, 0, stream>>>(go_bf, wb2, x, y1, M_, 1024, H_ * DV_, 1);
  rmsnorm_k<<<dim3(M_), blk256, 0, stream>>>(y1, n2w, nullptr, h2_bf, D_, 1e-6f);
  transpose_bf16_k<<<g_tr1024_2816, blk256, 0, stream>>>(W1, wb2, D_, FH_);
  mfma_gemm_k<128><<<dim3(FH_ / 128, M_ / 128), blk256, 0, stream>>>(h2_bf, wb2, nullptr, a1, M_, FH_, D_, 0);
  transpose_bf16_k<<<g_tr1024_2816, blk256, 0, stream>>>(W3, wb2, D_, FH_);
  mfma_gemm_k<128><<<dim3(FH_ / 128, M_ / 128), blk256, 0, stream>>>(h2_bf, wb2, a1, a1b, M_, FH_, D_, 2);
  transpose_bf16_k<<<g_tr2816_1024, blk256, 0, stream>>>(W2, wb2, FH_, 1024);
  mfma_gemm_k<64><<<dim3(1024 / 64, M_ / 128), blk256, 0, stream>>>(a1b, wb2, y1, out, M_, 1024, FH_, 1);
}

// Round 3
// 705.108 us; speedup vs baseline: 1.0151x; 1.0151x over previous
//
#include <hip/hip_runtime.h>
#include <hip/hip_bf16.h>
#include <math.h>

// Problem constants
#define B_  2
#define T_  1024
#define D_  1024
#define H_  16
#define DK_ 64
#define DV_ 128
#define FH_ 2816
#define M_  (B_ * T_)   // 2048 tokens
#define C_  64          // chunk length
#define NCH (T_ / C_)   // 16 chunks

typedef __attribute__((ext_vector_type(8))) short bf16x8;
typedef __attribute__((ext_vector_type(4))) float f32x4;

// ---------------------------------------------------------------------------
// rmsnorm with fp32 and/or bf16 outputs (either may be null)
__global__ __launch_bounds__(256) void rmsnorm_k(
    const float* __restrict__ x, const float* __restrict__ w,
    float* __restrict__ outf, __hip_bfloat16* __restrict__ outb,
    int D, float eps) {
  const int row = blockIdx.x;
  const float* xr = x + (size_t)row * D;
  float ss = 0.f;
  for (int i = threadIdx.x; i < D; i += blockDim.x) { float v = xr[i]; ss += v * v; }
  for (int off = 32; off > 0; off >>= 1) ss += __shfl_xor(ss, off, 64);
  __shared__ float wsum[4];
  __shared__ float s_scale;
  const int lane = threadIdx.x & 63, wid = threadIdx.x >> 6;
  if (lane == 0) wsum[wid] = ss;
  __syncthreads();
  if (threadIdx.x == 0) {
    float tot = 0.f;
    const int nw = blockDim.x >> 6;
    for (int i = 0; i < nw; ++i) tot += wsum[i];
    s_scale = rsqrtf(tot / (float)D + eps);
  }
  __syncthreads();
  const float sc = s_scale;
  for (int i = threadIdx.x; i < D; i += blockDim.x) {
    const float v = xr[i] * sc * w[i];
    if (outf) outf[(size_t)row * D + i] = v;
    if (outb) outb[(size_t)row * D + i] = __float2bfloat16(v);
  }
}

// ---------------------------------------------------------------------------
// Tiled transpose + fp32->bf16 convert: W[K,N] -> Wt[N,K]
__global__ __launch_bounds__(256) void transpose_bf16_k(
    const float* __restrict__ W, __hip_bfloat16* __restrict__ Wt, int K, int N) {
  __shared__ float t[32][33];
  const int k0 = blockIdx.y * 32, n0 = blockIdx.x * 32;
  const int c = threadIdx.x & 31, r = threadIdx.x >> 5;  // r in 0..7
#pragma unroll
  for (int i = 0; i < 4; ++i)
    t[r + 8 * i][c] = W[(size_t)(k0 + r + 8 * i) * N + n0 + c];
  __syncthreads();
#pragma unroll
  for (int i = 0; i < 4; ++i)
    Wt[(size_t)(n0 + r + 8 * i) * K + k0 + c] = __float2bfloat16(t[c][r + 8 * i]);
}

// ---------------------------------------------------------------------------
__device__ __forceinline__ void gload_lds16(const void* g, void* l) {
  __builtin_amdgcn_global_load_lds(
      (const __attribute__((address_space(1))) void*)g,
      (__attribute__((address_space(3))) void*)l, 16, 0, 0);
}

// bf16 MFMA GEMM: C[M,N] = A[M,K] @ Bt[N,K]^T.  Tile 128 x BN (BN=128 or 64).
// BN=64 doubles the grid for N=1024 shapes (128 WGs only covered half the CUs).
// mode 0: C = acc (fp32); mode 1: C = acc + res (fp32);
// mode 2: Cbf16 = silu(res) * acc   (fused SwiGLU epilogue)
template<int BN>
__global__ __launch_bounds__(256) void mfma_gemm_k(
    const __hip_bfloat16* __restrict__ A, const __hip_bfloat16* __restrict__ Bt,
    const float* __restrict__ res, void* __restrict__ Cout,
    int M, int N, int K, int mode) {
  __shared__ __hip_bfloat16 As[128 * 32];
  __shared__ __hip_bfloat16 Bs[BN * 32];
  constexpr int NF = BN / 32;        // b-frags per wave (4 or 2)
  const int tid = threadIdx.x;
  const int lane = tid & 63;
  const int wv = tid >> 6;
  const int wm = (wv >> 1) * 64, wn = (wv & 1) * (BN / 2);
  const int bm = blockIdx.y * 128, bn = blockIdx.x * BN;
  const int l15 = lane & 15, lq8 = (lane >> 4) * 8;
  const int ar = tid >> 2;
  const int ac = (tid & 3) * 8;
  const size_t Abase = (size_t)(bm + ar) * K + ac;
  const size_t Bbase = (size_t)(bn + ar) * K + ac;
  f32x4 acc[4][NF];
#pragma unroll
  for (int i = 0; i < 4; ++i)
#pragma unroll
    for (int j = 0; j < NF; ++j) acc[i][j] = (f32x4){0.f, 0.f, 0.f, 0.f};
  for (int k0 = 0; k0 < K; k0 += 32) {
    gload_lds16(A + Abase + k0, (char*)As + tid * 16);
    gload_lds16(A + Abase + (size_t)64 * K + k0, (char*)As + tid * 16 + 4096);
    gload_lds16(Bt + Bbase + k0, (char*)Bs + tid * 16);
    if (BN == 128)
      gload_lds16(Bt + Bbase + (size_t)64 * K + k0, (char*)Bs + tid * 16 + 4096);
    __syncthreads();
    bf16x8 af[4], bfr[NF];
#pragma unroll
    for (int i = 0; i < 4; ++i)
      af[i] = *(const bf16x8*)(As + (wm + i * 16 + l15) * 32 + lq8);
#pragma unroll
    for (int j = 0; j < NF; ++j)
      bfr[j] = *(const bf16x8*)(Bs + (wn + j * 16 + l15) * 32 + lq8);
#pragma unroll
    for (int i = 0; i < 4; ++i)
#pragma unroll
      for (int j = 0; j < NF; ++j)
        acc[i][j] = __builtin_amdgcn_mfma_f32_16x16x32_bf16(af[i], bfr[j], acc[i][j], 0, 0, 0);
    __syncthreads();
  }
  const int r0 = (lane >> 4) * 4;
#pragma unroll
  for (int i = 0; i < 4; ++i) {
#pragma unroll
    for (int j = 0; j < NF; ++j) {
      const int row = bm + wm + i * 16 + r0;
      const int col = bn + wn + j * 16 + l15;
#pragma unroll
      for (int r = 0; r < 4; ++r) {
        const size_t idx = (size_t)(row + r) * N + col;
        const float a = acc[i][j][r];
        if (mode == 0) ((float*)Cout)[idx] = a;
        else if (mode == 1) ((float*)Cout)[idx] = a + res[idx];
        else {
          const float s = res[idx];
          ((__hip_bfloat16*)Cout)[idx] =
              __float2bfloat16(s * (1.f / (1.f + __expf(-s))) * a);
        }
      }
    }
  }
}

// ---------------------------------------------------------------------------
// pa/pb = h @ [Wa|Wb] — all 256 threads active (8-way K-split + reduce).
__global__ __launch_bounds__(256) void skinny_k(
    const float* __restrict__ h, const float* __restrict__ Wa,
    const float* __restrict__ Wb, float* __restrict__ pa,
    float* __restrict__ pb, int K) {
  __shared__ float hl[D_];
  __shared__ float red[8][32];
  const int row = blockIdx.x;
  const int tid = threadIdx.x;
  {
    const float4* src = (const float4*)(h + (size_t)row * K);
    ((float4*)hl)[tid] = src[tid];
  }
  __syncthreads();
  const int col = tid & 31, sub = tid >> 5;
  const float* W = (col < 16) ? Wa : Wb;
  const int cc = col & 15;
  float s = 0.f;
  const int kk0 = sub * 128;
  for (int k = kk0; k < kk0 + 128; ++k) s += hl[k] * W[k * H_ + cc];
  red[sub][col] = s;
  __syncthreads();
  if (tid < 32) {
    float t = 0.f;
#pragma unroll
    for (int i = 0; i < 8; ++i) t += red[i][tid];
    if (tid < 16) pa[(size_t)row * H_ + tid] = t;
    else          pb[(size_t)row * H_ + tid - 16] = t;
  }
}

// ---------------------------------------------------------------------------
__global__ __launch_bounds__(256) void conv_silu_k(
    const float* __restrict__ src, const float* __restrict__ w,
    float* __restrict__ dst, int C) {
  const int bt = blockIdx.x;
  const int b = bt / T_, t = bt % T_;
  const float* s = src + (size_t)b * T_ * C;
  for (int c = threadIdx.x; c < C; c += blockDim.x) {
    const float w0 = w[c * 4 + 0], w1 = w[c * 4 + 1],
                w2 = w[c * 4 + 2], w3 = w[c * 4 + 3];
    float acc = s[(size_t)t * C + c] * w3;
    if (t >= 1) acc += s[(size_t)(t - 1) * C + c] * w2;
    if (t >= 2) acc += s[(size_t)(t - 2) * C + c] * w1;
    if (t >= 3) acc += s[(size_t)(t - 3) * C + c] * w0;
    dst[(size_t)bt * C + c] = acc * (1.f / (1.f + __expf(-acc)));
  }
}

// ---------------------------------------------------------------------------
__global__ void beta_g_k(const float* __restrict__ pa, const float* __restrict__ pb,
                         const float* __restrict__ dtb, const float* __restrict__ Alog,
                         float* __restrict__ g, float* __restrict__ beta, int n) {
  const int i = blockIdx.x * blockDim.x + threadIdx.x;
  if (i >= n) return;
  const int h = i & (H_ - 1);
  const float xx = pa[i] + dtb[h];
  const float sp = (xx > 20.f) ? xx : log1pf(expf(xx));
  g[i] = -expf(Alog[h]) * sp;
  beta[i] = 1.f / (1.f + expf(-pb[i]));
}

// ---------------------------------------------------------------------------
__global__ __launch_bounds__(64) void l2norm_k(float* __restrict__ q, float scale) {
  const size_t row = blockIdx.x;
  const int lane = threadIdx.x;
  const float v = q[row * 64 + lane];
  float ss = v * v;
  for (int off = 32; off > 0; off >>= 1) ss += __shfl_xor(ss, off, 64);
  q[row * 64 + lane] = v * rsqrtf(ss + 1e-6f) * scale;
}

// ---------------------------------------------------------------------------
// Chunked gated delta rule, phase A v3 (parallel over 512 (bh,chunk) tasks).
// Builds G (β-folded strict-lower decay Gram), QKd (->qkd), KdT (->kdt), γ.
// Then solves (I+G)X = RHS directly via BLOCKED forward substitution:
// 16x16 diagonal-block inverses Td (per-thread register triangles), then a
// 4-stage dense sweep over 96-column halves in LDS. Replaces round-4/6's
// Neumann doubling (10 x 64^3 matmuls -> ~1M MACs total, 4x less VALU).
// Outputs: u = X (in place over v), W = X (in place over k).
__global__ __launch_bounds__(256) void chunk_prep_k(
    const float* __restrict__ q, float* __restrict__ k, float* __restrict__ v,
    const float* __restrict__ g, const float* __restrict__ beta,
    float* __restrict__ qkd, float* __restrict__ kdt, float* __restrict__ gam) {
  const int task = blockIdx.x;
  const int bh = task >> 4, n = task & (NCH - 1);
  const int b = bh >> 4, h = bh & 15;
  const int t0 = n * C_;
  const int tid = threadIdx.x;
  __shared__ float lk[C_][68];     // staged k rows
  __shared__ float Gs[C_][68];     // strict-lower β-folded Gram (zeros above)
  __shared__ float Xs[C_][100];    // 96-column RHS/solution panel
  __shared__ float Td[4][16][17];  // 16x16 diagonal-block inverses
  __shared__ float lb[C_], lgam[C_], lbeta[C_], lbg[C_];
  // stage k chunk
  {
    const int r = tid >> 2, cq = (tid & 3) * 16;
    const float* src = k + (((size_t)b * T_ + t0 + r) * H_ + h) * DK_ + cq;
#pragma unroll
    for (int i = 0; i < 4; ++i)
      *(float4*)&lk[r][cq + 4 * i] = ((const float4*)src)[i];
  }
  // g cumsum (wave 0), γ, β, βγ
  if (tid < 64) {
    const size_t gi = ((size_t)b * T_ + t0 + tid) * H_ + h;
    float xx = g[gi];
    const float bb = beta[gi];
    lbeta[tid] = bb;
#pragma unroll
    for (int off = 1; off < 64; off <<= 1) {
      float y = __shfl_up(xx, off, 64);
      if (tid >= off) xx += y;
    }
    lb[tid] = xx;
    const float gm = __expf(xx);
    lgam[tid] = gm;
    lbg[tid] = bb * gm;
  }
  __syncthreads();
  const int r4g = (tid >> 4) * 4;
  const int sl = tid & 15;
  // Gram: G = β-folded strict-lower K K^T decay; QKd = (Q K^T) decay
  {
    const float* qg = q + (((size_t)b * T_ + t0) * H_ + h) * DK_;
    float accA[4][4] = {};
    float accQ[4][4] = {};
    for (int d = 0; d < 64; d += 4) {
      float4 kt[4], ks[4], qt[4];
#pragma unroll
      for (int i = 0; i < 4; ++i) kt[i] = *(const float4*)&lk[r4g + i][d];
#pragma unroll
      for (int j = 0; j < 4; ++j) ks[j] = *(const float4*)&lk[sl + 16 * j][d];
#pragma unroll
      for (int i = 0; i < 4; ++i) qt[i] = *(const float4*)(qg + (size_t)(r4g + i) * (H_ * DK_) + d);
#pragma unroll
      for (int i = 0; i < 4; ++i)
#pragma unroll
        for (int j = 0; j < 4; ++j) {
          accA[i][j] += kt[i].x * ks[j].x + kt[i].y * ks[j].y + kt[i].z * ks[j].z + kt[i].w * ks[j].w;
          accQ[i][j] += qt[i].x * ks[j].x + qt[i].y * ks[j].y + qt[i].z * ks[j].z + qt[i].w * ks[j].w;
        }
    }
    float* qo = qkd + (size_t)task * 4096;
#pragma unroll
    for (int i = 0; i < 4; ++i)
#pragma unroll
      for (int j = 0; j < 4; ++j) {
        const int t = r4g + i, s = sl + 16 * j;
        const float dec = (s <= t) ? __expf(lb[t] - lb[s]) : 0.f;
        Gs[t][s] = (t > s) ? lbeta[t] * accA[i][j] * dec : 0.f;
        qo[t * 64 + s] = accQ[i][j] * dec;
      }
  }
  // KdT and γ out
  {
    const int dk = tid >> 2, s0 = (tid & 3) * 16;
    const float bC = lb[63];
    float* dst = kdt + (size_t)task * 4096 + dk * 64 + s0;
#pragma unroll
    for (int j = 0; j < 16; ++j)
      dst[j] = lk[s0 + j][dk] * __expf(bC - lb[s0 + j]);
  }
  if (tid < 64) gam[(size_t)task * 64 + tid] = lgam[tid];
  __syncthreads();
  // Td (threads 0..63: 4 blocks x 16 columns, registers only) + RHS0 load
  if (tid < 64) {
    const int blk = tid >> 4, cI = tid & 15;
    float Xc[16];
#pragma unroll
    for (int t = 0; t < 16; ++t) Xc[t] = (t == cI) ? 1.f : 0.f;
#pragma unroll
    for (int t = 1; t < 16; ++t) {
      float acc = 0.f;
#pragma unroll
      for (int s = 0; s < t; ++s)
        acc += Gs[blk * 16 + t][blk * 16 + s] * Xc[s];
      Xc[t] -= acc;
    }
#pragma unroll
    for (int t = 0; t < 16; ++t) Td[blk][t][cI] = Xc[t];
  } else {
    // RHS half 0: βV columns 0..95 (192 threads, 32 cells each)
    for (int idx = tid - 64; idx < 64 * 96; idx += 192) {
      const int t = idx / 96, c = idx % 96;
      Xs[t][c] = lbeta[t] * v[(((size_t)b * T_ + t0 + t) * H_ + h) * DV_ + c];
    }
  }
  __syncthreads();
  const int rt = tid & 15;          // row within block
  const int cg = tid >> 4;          // column group: cols cg*6 .. cg*6+5
#pragma unroll 1
  for (int half = 0; half < 2; ++half) {
    // 4-stage blocked sweep
#pragma unroll
    for (int bi = 0; bi < 4; ++bi) {
      if (bi > 0) {
        float acc[6] = {0.f, 0.f, 0.f, 0.f, 0.f, 0.f};
        for (int kk = 0; kk < 16 * bi; ++kk) {
          const float gvv = Gs[16 * bi + rt][kk];
#pragma unroll
          for (int c = 0; c < 6; ++c) acc[c] += gvv * Xs[kk][cg * 6 + c];
        }
#pragma unroll
        for (int c = 0; c < 6; ++c) Xs[16 * bi + rt][cg * 6 + c] -= acc[c];
      }
      __syncthreads();
      float y[6] = {0.f, 0.f, 0.f, 0.f, 0.f, 0.f};
#pragma unroll
      for (int s = 0; s < 16; ++s) {
        const float tv = Td[bi][rt][s];
#pragma unroll
        for (int c = 0; c < 6; ++c) y[c] += tv * Xs[16 * bi + s][cg * 6 + c];
      }
      __syncthreads();
#pragma unroll
      for (int c = 0; c < 6; ++c) Xs[16 * bi + rt][cg * 6 + c] = y[c];
      __syncthreads();
    }
    // writeback + next RHS
    if (half == 0) {
      for (int idx = tid; idx < 64 * 96; idx += 256) {
        const int t = idx / 96, c = idx % 96;
        v[(((size_t)b * T_ + t0 + t) * H_ + h) * DV_ + c] = Xs[t][c];
      }
      __syncthreads();
      // RHS half 1: cols 0..31 = βV cols 96..127; cols 32..95 = βγ·K cols 0..63
      for (int idx = tid; idx < 64 * 96; idx += 256) {
        const int t = idx / 96, c = idx % 96;
        if (c < 32)
          Xs[t][c] = lbeta[t] * v[(((size_t)b * T_ + t0 + t) * H_ + h) * DV_ + 96 + c];
        else
          Xs[t][c] = lbg[t] * lk[t][c - 32];
      }
      __syncthreads();
    } else {
      for (int idx = tid; idx < 64 * 96; idx += 256) {
        const int t = idx / 96, c = idx % 96;
        if (c < 32)
          v[(((size_t)b * T_ + t0 + t) * H_ + h) * DV_ + 96 + c] = Xs[t][c];
        else
          k[(((size_t)b * T_ + t0 + t) * H_ + h) * DK_ + c - 32] = Xs[t][c];
      }
    }
  }
}

// ---------------------------------------------------------------------------
// Serial recurrence — round 8: SAME-ITERATION load/use split + double-buffered
// LDS. Round-7 failed (VGPR stayed 132: loads in a guarded BB with uses across
// the back-edge were legally sunk by the compiler, reverting to baseline).
// Fix: single straight-line loop body (clamped n+1, no branch). Loads issue at
// top, their consuming LDS-commits sit AFTER the matmuls, so the vmcnt waits
// are covered by ~2048cy of FMAs. sched_barrier(0) fences pin the issue points
// (pressure-aware scheduler would otherwise sink the 64-VGPR load batches back
// to their uses). U = rU - (W@S) ordering moves the u-load use after matmul1.
__global__ __launch_bounds__(64) void chunk_rec_k(
    const float* __restrict__ W, float* __restrict__ u,
    const float* __restrict__ kdt, const float* __restrict__ gam,
    float* __restrict__ Sst) {
  const int bh = blockIdx.x >> 3, cg = blockIdx.x & 7;
  const int b = bh >> 4, h = bh & 15;
  const int c0 = cg * 16;
  const int lane = threadIdx.x;
  const int r4 = (lane & 15) * 4;
  const int cl = (lane >> 4) * 4;
  __shared__ float Wt[2][64][68];
  __shared__ float Kt[2][64][68];
  __shared__ float Ss[64][20];
  __shared__ float Ub[64][20];
  float Sr[4][4];
#pragma unroll
  for (int i = 0; i < 4; ++i)
#pragma unroll
    for (int j = 0; j < 4; ++j) Sr[i][j] = 0.f;
  for (int i = lane; i < 64 * 20; i += 64) (&Ss[0][0])[i] = 0.f;

  // prologue: stage chunk 0 into buffer 0
  {
    const float* srcW = W + (((size_t)b * T_ + lane) * H_ + h) * DK_;
    const float* srcK = kdt + (size_t)(bh * NCH) * 4096 + lane * 64;
    float4 rW[16], rK[16];
#pragma unroll
    for (int i = 0; i < 16; ++i) rW[i] = ((const float4*)srcW)[i];
#pragma unroll
    for (int i = 0; i < 16; ++i) rK[i] = ((const float4*)srcK)[i];
#pragma unroll
    for (int d4 = 0; d4 < 16; ++d4) {
      Wt[0][4 * d4 + 0][lane] = rW[d4].x; Wt[0][4 * d4 + 1][lane] = rW[d4].y;
      Wt[0][4 * d4 + 2][lane] = rW[d4].z; Wt[0][4 * d4 + 3][lane] = rW[d4].w;
      Kt[0][4 * d4 + 0][lane] = rK[d4].x; Kt[0][4 * d4 + 1][lane] = rK[d4].y;
      Kt[0][4 * d4 + 2][lane] = rK[d4].z; Kt[0][4 * d4 + 3][lane] = rK[d4].w;
    }
  }

#pragma unroll 1
  for (int n = 0; n < NCH; ++n) {
    const int cur = n & 1, nx = cur ^ 1;
    const int task = bh * NCH + n;
    const int t0 = n * C_;
    const int n1 = (n + 1 < NCH) ? (n + 1) : (NCH - 1);   // clamp: no branch BB
    const int t1 = n1 * C_;
    const int task1 = bh * NCH + n1;
    const float gC = gam[(size_t)task * 64 + 63];
    // A) issue this-chunk u loads + next-chunk W loads (consumed after matmul1)
    float4 rU[4];
#pragma unroll
    for (int i = 0; i < 4; ++i)
      rU[i] = *(const float4*)(u + (((size_t)b * T_ + t0 + r4 + i) * H_ + h) * DV_ + c0 + cl);
    float4 rW[16];
    {
      const float* srcW = W + (((size_t)b * T_ + t1 + lane) * H_ + h) * DK_;
#pragma unroll
      for (int i = 0; i < 16; ++i) rW[i] = ((const float4*)srcW)[i];
    }
    __builtin_amdgcn_sched_barrier(0);
    // B) state snapshot out (pre-chunk state, consumed by chunk_o_k)
#pragma unroll
    for (int i = 0; i < 4; ++i)
      *(float4*)(Sst + (size_t)task * 8192 + (r4 + i) * 128 + c0 + cl) =
          make_float4(Sr[i][0], Sr[i][1], Sr[i][2], Sr[i][3]);
    // C) matmul1: acc = W @ S   (reads Wt[cur]; ~2048cy covers rU/rW latency)
    float acc[4][4] = {};
    for (int kb = 0; kb < 64; kb += 4) {
#pragma unroll
      for (int j = 0; j < 4; ++j) {
        const float4 a = *(const float4*)&Wt[cur][kb + j][r4];
        const float4 bb = *(const float4*)&Ss[kb + j][cl];
        const float av[4] = {a.x, a.y, a.z, a.w};
        const float bv[4] = {bb.x, bb.y, bb.z, bb.w};
#pragma unroll
        for (int i = 0; i < 4; ++i)
#pragma unroll
          for (int c = 0; c < 4; ++c) acc[i][c] += av[i] * bv[c];
      }
    }
    __builtin_amdgcn_sched_barrier(0);
    // D) U = u - W@S: write Ub (LDS) + u (global)
#pragma unroll
    for (int i = 0; i < 4; ++i) {
      const float u0 = rU[i].x - acc[i][0], u1 = rU[i].y - acc[i][1];
      const float u2 = rU[i].z - acc[i][2], u3 = rU[i].w - acc[i][3];
      *(float4*)&Ub[r4 + i][cl] = make_float4(u0, u1, u2, u3);
      *(float4*)(u + (((size_t)b * T_ + t0 + r4 + i) * H_ + h) * DV_ + c0 + cl) =
          make_float4(u0, u1, u2, u3);
    }
    // E) commit rW -> Wt[nx]  (vmcnt(0) wait lands here, already covered)
#pragma unroll
    for (int d4 = 0; d4 < 16; ++d4) {
      Wt[nx][4 * d4 + 0][lane] = rW[d4].x; Wt[nx][4 * d4 + 1][lane] = rW[d4].y;
      Wt[nx][4 * d4 + 2][lane] = rW[d4].z; Wt[nx][4 * d4 + 3][lane] = rW[d4].w;
    }
    // F) issue next-chunk kdt loads (consumed after matmul2)
    float4 rK[16];
    {
      const float* srcK = kdt + (size_t)task1 * 4096 + lane * 64;
#pragma unroll
      for (int i = 0; i < 16; ++i) rK[i] = ((const float4*)srcK)[i];
    }
    __builtin_amdgcn_sched_barrier(0);
    // G) matmul2: acc2 = K̂ᵀ @ U   (reads Kt[cur]; covers rK latency)
    float acc2[4][4] = {};
    for (int sb = 0; sb < 64; sb += 4) {
#pragma unroll
      for (int j = 0; j < 4; ++j) {
        const float4 a = *(const float4*)&Kt[cur][sb + j][r4];
        const float4 bb = *(const float4*)&Ub[sb + j][cl];
        const float av[4] = {a.x, a.y, a.z, a.w};
        const float bv[4] = {bb.x, bb.y, bb.z, bb.w};
#pragma unroll
        for (int i = 0; i < 4; ++i)
#pragma unroll
          for (int c = 0; c < 4; ++c) acc2[i][c] += av[i] * bv[c];
      }
    }
    __builtin_amdgcn_sched_barrier(0);
    // H) state update + Ss write
#pragma unroll
    for (int i = 0; i < 4; ++i) {
#pragma unroll
      for (int c = 0; c < 4; ++c) Sr[i][c] = gC * Sr[i][c] + acc2[i][c];
      *(float4*)&Ss[r4 + i][cl] = make_float4(Sr[i][0], Sr[i][1], Sr[i][2], Sr[i][3]);
    }
    // I) commit rK -> Kt[nx]  (vmcnt(0) wait lands here, covered by matmul2)
#pragma unroll
    for (int s4 = 0; s4 < 16; ++s4) {
      Kt[nx][4 * s4 + 0][lane] = rK[s4].x; Kt[nx][4 * s4 + 1][lane] = rK[s4].y;
      Kt[nx][4 * s4 + 2][lane] = rK[s4].z; Kt[nx][4 * s4 + 3][lane] = rK[s4].w;
    }
  }
}

// ---------------------------------------------------------------------------
// Parallel O with fused gatenorm (unchanged from round 6).
__global__ __launch_bounds__(128) void chunk_o_k(
    const float* __restrict__ q, const float* __restrict__ qkd,
    const float* __restrict__ ub, const float* __restrict__ Sst,
    const float* __restrict__ gam, const float* __restrict__ gate,
    const float* __restrict__ onw, __hip_bfloat16* __restrict__ go) {
  const int task = blockIdx.x;
  const int bh = task >> 4, n = task & 15;
  const int b = bh >> 4, h = bh & 15;
  const int t0 = n * C_;
  const int tid = threadIdx.x;
  const int rowg = tid >> 4, colg = tid & 15;
  const int r8 = rowg * 8, c4 = colg * 4;
  __shared__ float At[64][68];
  __shared__ float Bs[64][132];
  __shared__ float lgam[64];
  if (tid < 64) lgam[tid] = gam[(size_t)task * 64 + tid];
  __syncthreads();
  const int t2 = tid >> 1, dh = (tid & 1) * 32;
  {
    const float* src = q + (((size_t)b * T_ + t0 + t2) * H_ + h) * DK_ + dh;
    const float sc = lgam[t2];
#pragma unroll
    for (int i = 0; i < 8; ++i) {
      const float4 v = ((const float4*)src)[i];
      At[dh + 4 * i + 0][t2] = v.x * sc; At[dh + 4 * i + 1][t2] = v.y * sc;
      At[dh + 4 * i + 2][t2] = v.z * sc; At[dh + 4 * i + 3][t2] = v.w * sc;
    }
  }
  {
    const float* src = Sst + (size_t)task * 8192 + t2 * 128 + (tid & 1) * 64;
    float* dst = &Bs[t2][(tid & 1) * 64];
#pragma unroll
    for (int i = 0; i < 16; ++i) ((float4*)dst)[i] = ((const float4*)src)[i];
  }
  __syncthreads();
  float acc[8][8];
#pragma unroll
  for (int i = 0; i < 8; ++i)
#pragma unroll
    for (int c = 0; c < 8; ++c) acc[i][c] = 0.f;
#pragma unroll 1
  for (int ph = 0; ph < 2; ++ph) {
    for (int kb = 0; kb < 64; kb += 4) {
#pragma unroll
      for (int j = 0; j < 4; ++j) {
        const float4 alo = *(const float4*)&At[kb + j][r8];
        const float4 ahi = *(const float4*)&At[kb + j][r8 + 4];
        const float4 blo = *(const float4*)&Bs[kb + j][c4];
        const float4 bhi = *(const float4*)&Bs[kb + j][c4 + 64];
        const float av[8] = {alo.x, alo.y, alo.z, alo.w, ahi.x, ahi.y, ahi.z, ahi.w};
        const float bv[8] = {blo.x, blo.y, blo.z, blo.w, bhi.x, bhi.y, bhi.z, bhi.w};
#pragma unroll
        for (int i = 0; i < 8; ++i)
#pragma unroll
          for (int c = 0; c < 8; ++c) acc[i][c] += av[i] * bv[c];
      }
    }
    if (ph == 0) {
      __syncthreads();
      {
        const float* src = qkd + (size_t)task * 4096 + t2 * 64 + dh;
#pragma unroll
        for (int i = 0; i < 8; ++i) {
          const float4 v = ((const float4*)src)[i];
          At[dh + 4 * i + 0][t2] = v.x; At[dh + 4 * i + 1][t2] = v.y;
          At[dh + 4 * i + 2][t2] = v.z; At[dh + 4 * i + 3][t2] = v.w;
        }
      }
      {
        const float* src = ub + (((size_t)b * T_ + t0 + t2) * H_ + h) * DV_ + (tid & 1) * 64;
        float* dst = &Bs[t2][(tid & 1) * 64];
#pragma unroll
        for (int i = 0; i < 16; ++i) ((float4*)dst)[i] = ((const float4*)src)[i];
      }
      __syncthreads();
    }
  }
#pragma unroll
  for (int i = 0; i < 8; ++i) {
    float pr = 0.f;
#pragma unroll
    for (int c = 0; c < 8; ++c) pr += acc[i][c] * acc[i][c];
    pr += __shfl_xor(pr, 1, 64);
    pr += __shfl_xor(pr, 2, 64);
    pr += __shfl_xor(pr, 4, 64);
    pr += __shfl_xor(pr, 8, 64);
    const float rms = rsqrtf(pr / (float)DV_ + 1e-5f);
    const size_t rb = (((size_t)b * T_ + t0 + r8 + i) * H_ + h) * DV_;
    const float4 glo = *(const float4*)(gate + rb + c4);
    const float4 ghi = *(const float4*)(gate + rb + c4 + 64);
    const float gv[8] = {glo.x, glo.y, glo.z, glo.w, ghi.x, ghi.y, ghi.z, ghi.w};
    unsigned short outv[8];
#pragma unroll
    for (int c = 0; c < 8; ++c) {
      const int col = (c < 4) ? c4 + c : c4 + 60 + c;
      const float gg = gv[c];
      const float val = acc[i][c] * rms * onw[col] * gg * (1.f / (1.f + __expf(-gg)));
      const __hip_bfloat16 bfv = __float2bfloat16(val);
      outv[c] = *(const unsigned short*)&bfv;
    }
    *(ushort4*)((unsigned short*)go + rb + c4) =
        make_ushort4(outv[0], outv[1], outv[2], outv[3]);
    *(ushort4*)((unsigned short*)go + rb + c4 + 64) =
        make_ushort4(outv[4], outv[5], outv[6], outv[7]);
  }
}

// ---------------------------------------------------------------------------
extern "C" void kernel_launch(void* const* d_in, const int* in_sizes, int n_in,
                              void* d_out, int out_size, void* d_ws, size_t ws_size,
                              hipStream_t stream) {
  const float* x    = (const float*)d_in[0];
  const float* n1w  = (const float*)d_in[1];
  const float* n2w  = (const float*)d_in[2];
  const float* Wq   = (const float*)d_in[3];
  const float* Wk   = (const float*)d_in[4];
  const float* Wv   = (const float*)d_in[5];
  const float* cq   = (const float*)d_in[6];
  const float* ck   = (const float*)d_in[7];
  const float* cv   = (const float*)d_in[8];
  const float* Wa   = (const float*)d_in[9];
  const float* Wb   = (const float*)d_in[10];
  const float* dtb  = (const float*)d_in[11];
  const float* Alog = (const float*)d_in[12];
  const float* Wg   = (const float*)d_in[13];
  const float* onw  = (const float*)d_in[14];
  const float* Wo   = (const float*)d_in[15];
  const float* W1   = (const float*)d_in[16];
  const float* W3   = (const float*)d_in[17];
  const float* W2   = (const float*)d_in[18];
  float* out = (float*)d_out;
  float* ws  = (float*)d_ws;

  const size_t SZ_MD = (size_t)M_ * D_;          // 2M floats
  const size_t SZ_MV = (size_t)M_ * H_ * DV_;    // 4M floats
  float* h    = ws;                               // [0,2M)
  float* pq   = ws + SZ_MD;                       // [2M,4M)  -> QKd -> y1
  float* pk   = ws + 2 * SZ_MD;                   // [4M,6M)  -> KdT
  float* pv   = ws + 3 * SZ_MD;                   // [6M,10M) -> S_store -> a1
  float* gate = ws + 3 * SZ_MD + SZ_MV;           // [10M,14M)
  float* qb   = ws + 3 * SZ_MD + 2 * SZ_MV;       // [14M,16M)
  float* kb   = ws + 4 * SZ_MD + 2 * SZ_MV;       // [16M,18M) in-place W
  float* vb   = ws + 5 * SZ_MD + 2 * SZ_MV;       // [18M,22M) in-place u -> Û
  float* Sst  = pv;
  float* y1   = pq;
  float* a1   = pv;
  float* smalls = ws + 5 * SZ_MD + 3 * SZ_MV;     // 22M
  float* pa  = smalls;
  float* pb  = pa + (size_t)M_ * H_;
  float* gv  = pb + (size_t)M_ * H_;
  float* bv  = gv + (size_t)M_ * H_;
  float* gam = bv + (size_t)M_ * H_;
  __hip_bfloat16* h_bf  = (__hip_bfloat16*)vb;
  __hip_bfloat16* wb1   = (__hip_bfloat16*)kb;
  __hip_bfloat16* wb2   = (__hip_bfloat16*)vb;
  __hip_bfloat16* go_bf = (__hip_bfloat16*)h;
  __hip_bfloat16* h2_bf = (__hip_bfloat16*)h;
  __hip_bfloat16* a1b   = (__hip_bfloat16*)qb;

  const dim3 blk256(256);
  const dim3 g_tr1024_1024(1024 / 32, 1024 / 32);
  const dim3 g_tr1024_2048(2048 / 32, 1024 / 32);
  const dim3 g_tr2048_1024(1024 / 32, 2048 / 32);
  const dim3 g_tr1024_2816(2816 / 32, 1024 / 32);
  const dim3 g_tr2816_1024(1024 / 32, 2816 / 32);

  rmsnorm_k<<<dim3(M_), blk256, 0, stream>>>(x, n1w, h, h_bf, D_, 1e-6f);
  transpose_bf16_k<<<g_tr1024_1024, blk256, 0, stream>>>(Wq, wb1, D_, 1024);
  mfma_gemm_k<64><<<dim3(1024 / 64, M_ / 128), blk256, 0, stream>>>(h_bf, wb1, nullptr, pq, M_, 1024, D_, 0);
  transpose_bf16_k<<<g_tr1024_1024, blk256, 0, stream>>>(Wk, wb1, D_, 1024);
  mfma_gemm_k<64><<<dim3(1024 / 64, M_ / 128), blk256, 0, stream>>>(h_bf, wb1, nullptr, pk, M_, 1024, D_, 0);
  transpose_bf16_k<<<g_tr1024_2048, blk256, 0, stream>>>(Wv, wb1, D_, 2048);
  mfma_gemm_k<128><<<dim3(2048 / 128, M_ / 128), blk256, 0, stream>>>(h_bf, wb1, nullptr, pv, M_, 2048, D_, 0);
  transpose_bf16_k<<<g_tr1024_2048, blk256, 0, stream>>>(Wg, wb1, D_, 2048);
  mfma_gemm_k<128><<<dim3(2048 / 128, M_ / 128), blk256, 0, stream>>>(h_bf, wb1, nullptr, gate, M_, 2048, D_, 0);
  skinny_k<<<dim3(M_), blk256, 0, stream>>>(h, Wa, Wb, pa, pb, D_);
  conv_silu_k<<<dim3(M_), blk256, 0, stream>>>(pq, cq, qb, H_ * DK_);
  conv_silu_k<<<dim3(M_), blk256, 0, stream>>>(pk, ck, kb, H_ * DK_);
  conv_silu_k<<<dim3(M_), blk256, 0, stream>>>(pv, cv, vb, H_ * DV_);
  beta_g_k<<<dim3((M_ * H_ + 255) / 256), blk256, 0, stream>>>(pa, pb, dtb, Alog, gv, bv, M_ * H_);
  l2norm_k<<<dim3(M_ * H_), dim3(64), 0, stream>>>(qb, 0.125f);
  l2norm_k<<<dim3(M_ * H_), dim3(64), 0, stream>>>(kb, 1.0f);
  chunk_prep_k<<<dim3(32 * NCH), blk256, 0, stream>>>(qb, kb, vb, gv, bv, pq, pk, gam);
  chunk_rec_k<<<dim3(32 * 8), dim3(64), 0, stream>>>(kb, vb, pk, gam, Sst);
  chunk_o_k<<<dim3(32 * NCH), dim3(128), 0, stream>>>(qb, pq, vb, Sst, gam, gate, onw, go_bf);
  transpose_bf16_k<<<g_tr2048_1024, blk256, 0, stream>>>(Wo, wb2, H_ * DV_, 1024);
  mfma_gemm_k<64><<<dim3(1024 / 64, M_ / 128), blk256, 0, stream>>>(go_bf, wb2, x, y1, M_, 1024, H_ * DV_, 1);
  rmsnorm_k<<<dim3(M_), blk256, 0, stream>>>(y1, n2w, nullptr, h2_bf, D_, 1e-6f);
  transpose_bf16_k<<<g_tr1024_2816, blk256, 0, stream>>>(W1, wb2, D_, FH_);
  mfma_gemm_k<128><<<dim3(FH_ / 128, M_ / 128), blk256, 0, stream>>>(h2_bf, wb2, nullptr, a1, M_, FH_, D_, 0);
  transpose_bf16_k<<<g_tr1024_2816, blk256, 0, stream>>>(W3, wb2, D_, FH_);
  mfma_gemm_k<128><<<dim3(FH_ / 128, M_ / 128), blk256, 0, stream>>>(h2_bf, wb2, a1, a1b, M_, FH_, D_, 2);
  transpose_bf16_k<<<g_tr2816_1024, blk256, 0, stream>>>(W2, wb2, FH_, 1024);
  mfma_gemm_k<64><<<dim3(1024 / 64, M_ / 128), blk256, 0, stream>>>(a1b, wb2, y1, out, M_, 1024, FH_, 1);
}